// Round 1
// baseline (1189.791 us; speedup 1.0000x reference)
//
#include <hip/hip_runtime.h>

#define LEAK 0.333f
#define BN_EPS 1e-4f

__device__ __forceinline__ float dot32(const float4 (&f)[8], const float (&w)[32]) {
    float a0 = 0.f, a1 = 0.f, a2 = 0.f, a3 = 0.f;
#pragma unroll
    for (int q = 0; q < 8; ++q) {
        a0 = fmaf(f[q].x, w[4 * q + 0], a0);
        a1 = fmaf(f[q].y, w[4 * q + 1], a1);
        a2 = fmaf(f[q].z, w[4 * q + 2], a2);
        a3 = fmaf(f[q].w, w[4 * q + 3], a3);
    }
    return (a0 + a1) + (a2 + a3);
}

// One wave per input: lane = output channel. Weights held in registers
// (W[k][c][lane] for all k,c -> 128 VGPRs). k is wave-uniform -> uniform branch.
__global__ __launch_bounds__(256) void scatter_conv_kernel(
    const float* __restrict__ feat, const float* __restrict__ weight,
    const int* __restrict__ out_idx, const int* __restrict__ kern_idx,
    float* __restrict__ out, int n_in)
{
    const int lane = threadIdx.x & 63;
    float w0[32], w1[32], w2[32], w3[32];
#pragma unroll
    for (int c = 0; c < 32; ++c) {
        w0[c] = weight[(0 * 32 + c) * 64 + lane];
        w1[c] = weight[(1 * 32 + c) * 64 + lane];
        w2[c] = weight[(2 * 32 + c) * 64 + lane];
        w3[c] = weight[(3 * 32 + c) * 64 + lane];
    }
    const int wid = (int)((blockIdx.x * blockDim.x + threadIdx.x) >> 6);
    const int nw  = (int)((gridDim.x * blockDim.x) >> 6);
    for (int i = wid; i < n_in; i += nw) {
        const int k = kern_idx[i];   // wave-uniform (same i for all 64 lanes)
        const int o = out_idx[i];
        const float4* f4 = (const float4*)(feat + (size_t)i * 32);
        float4 f[8];
#pragma unroll
        for (int q = 0; q < 8; ++q) f[q] = f4[q];
        float acc;
        if (k == 0)      acc = dot32(f, w0);
        else if (k == 1) acc = dot32(f, w1);
        else if (k == 2) acc = dot32(f, w2);
        else             acc = dot32(f, w3);
        atomicAdd(out + (size_t)o * 64 + lane, acc);  // coalesced 256B per wave
    }
}

// Column-wise sum & sum-of-squares over n_out rows (lane = channel, coalesced).
__global__ __launch_bounds__(256) void stats_kernel(
    const float* __restrict__ out, float* __restrict__ stats, int n_out)
{
    const int lane = threadIdx.x & 63;
    const int wave = threadIdx.x >> 6;
    const int gwave = blockIdx.x * 4 + wave;
    const int nwave = gridDim.x * 4;
    float s = 0.f, ss = 0.f;
    for (int r = gwave; r < n_out; r += nwave) {
        float v = out[(size_t)r * 64 + lane];
        s += v;
        ss = fmaf(v, v, ss);
    }
    __shared__ float ls[4][64];
    __shared__ float lq[4][64];
    ls[wave][lane] = s;
    lq[wave][lane] = ss;
    __syncthreads();
    if (wave == 0) {
        float ts = ls[0][lane] + ls[1][lane] + ls[2][lane] + ls[3][lane];
        float tq = lq[0][lane] + lq[1][lane] + lq[2][lane] + lq[3][lane];
        atomicAdd(&stats[lane], ts);
        atomicAdd(&stats[64 + lane], tq);
    }
}

__global__ void finalize_kernel(float* __restrict__ stats,
                                const float* __restrict__ gamma,
                                const float* __restrict__ beta, float inv_n)
{
    const int j = threadIdx.x;  // 64 threads
    float mean = stats[j] * inv_n;
    float var  = fmaf(-mean, mean, stats[64 + j] * inv_n);
    var = fmaxf(var, 0.f);
    float scale = gamma[j] * rsqrtf(var + BN_EPS);
    stats[128 + j] = scale;
    stats[192 + j] = beta[j] - mean * scale;
}

__global__ __launch_bounds__(256) void apply_kernel(
    float* __restrict__ out, const float* __restrict__ stats, int n4)
{
    __shared__ float sscale[64];
    __shared__ float sshift[64];
    if (threadIdx.x < 64) {
        sscale[threadIdx.x] = stats[128 + threadIdx.x];
        sshift[threadIdx.x] = stats[192 + threadIdx.x];
    }
    __syncthreads();
    const int idx = blockIdx.x * blockDim.x + threadIdx.x;
    const int stride = gridDim.x * blockDim.x;
    float4* o4 = (float4*)out;
    for (int i = idx; i < n4; i += stride) {
        const int cb = (i * 4) & 63;
        float4 v = o4[i];
        v.x = fmaf(v.x, sscale[cb + 0], sshift[cb + 0]);
        v.y = fmaf(v.y, sscale[cb + 1], sshift[cb + 1]);
        v.z = fmaf(v.z, sscale[cb + 2], sshift[cb + 2]);
        v.w = fmaf(v.w, sscale[cb + 3], sshift[cb + 3]);
        v.x = v.x > 0.f ? v.x : LEAK * v.x;
        v.y = v.y > 0.f ? v.y : LEAK * v.y;
        v.z = v.z > 0.f ? v.z : LEAK * v.z;
        v.w = v.w > 0.f ? v.w : LEAK * v.w;
        o4[i] = v;
    }
}

extern "C" void kernel_launch(void* const* d_in, const int* in_sizes, int n_in,
                              void* d_out, int out_size, void* d_ws, size_t ws_size,
                              hipStream_t stream)
{
    // Inputs: 0=features 1=weight 2=bias(unused: cancels in BN) 3=gamma 4=beta
    //         5=out_idx 6=kern_idx 7=n_out(unused: out_size/64)
    const float* feat    = (const float*)d_in[0];
    const float* weight  = (const float*)d_in[1];
    const float* gamma   = (const float*)d_in[3];
    const float* beta    = (const float*)d_in[4];
    const int*   out_idx = (const int*)d_in[5];
    const int*   kern_idx= (const int*)d_in[6];
    const int n_active = in_sizes[5];
    const int n_out    = out_size / 64;
    float* out   = (float*)d_out;
    float* stats = (float*)d_ws;

    hipMemsetAsync(d_out, 0, (size_t)out_size * sizeof(float), stream);
    hipMemsetAsync(d_ws, 0, 256 * sizeof(float), stream);

    scatter_conv_kernel<<<2048, 256, 0, stream>>>(feat, weight, out_idx, kern_idx,
                                                  out, n_active);
    stats_kernel<<<2048, 256, 0, stream>>>(out, stats, n_out);
    finalize_kernel<<<1, 64, 0, stream>>>(stats, gamma, beta, 1.0f / (float)n_out);
    apply_kernel<<<2048, 256, 0, stream>>>(out, stats, out_size / 4);
}

// Round 3
// 985.787 us; speedup vs baseline: 1.2069x; 1.2069x over previous
//
#include <hip/hip_runtime.h>

#define LEAK 0.333f
#define BN_EPS 1e-4f

#if __has_builtin(__builtin_amdgcn_fdot2) && __has_builtin(__builtin_amdgcn_cvt_pkrtz)
#define USE_FDOT2 1
#else
#define USE_FDOT2 0
#endif

typedef __fp16 h2 __attribute__((ext_vector_type(2)));

// ---------------------------------------------------------------------------
// fill: table[out_idx[i]*4 + kern_idx[i]] = i   (unique slots -> plain stores)
// ---------------------------------------------------------------------------
__global__ __launch_bounds__(256) void fill_table_kernel(
    const int* __restrict__ out_idx, const int* __restrict__ kern_idx,
    int* __restrict__ table, int n_in)
{
    const int i = blockIdx.x * 256 + threadIdx.x;
    if (i < n_in) {
        table[out_idx[i] * 4 + kern_idx[i]] = i;
    }
}

// ---------------------------------------------------------------------------
// gather conv + fused BN statistics
// one wave per output row; lane = output channel
// ---------------------------------------------------------------------------
#if USE_FDOT2
__device__ __forceinline__ float dot_row(const float* __restrict__ fp,
                                         const h2 (&w)[16], float acc)
{
    const float4* f4 = (const float4*)fp;
    float4 v[8];
#pragma unroll
    for (int q = 0; q < 8; ++q) v[q] = f4[q];
#pragma unroll
    for (int q = 0; q < 8; ++q) {
        h2 h0 = __builtin_amdgcn_cvt_pkrtz(v[q].x, v[q].y);
        h2 h1 = __builtin_amdgcn_cvt_pkrtz(v[q].z, v[q].w);
        acc = __builtin_amdgcn_fdot2(h0, w[2 * q + 0], acc, false);
        acc = __builtin_amdgcn_fdot2(h1, w[2 * q + 1], acc, false);
    }
    return acc;
}
#else
__device__ __forceinline__ float dot_row(const float* __restrict__ fp,
                                         const float (&w)[32], float acc)
{
    const float4* f4 = (const float4*)fp;
    float4 v[8];
#pragma unroll
    for (int q = 0; q < 8; ++q) v[q] = f4[q];
#pragma unroll
    for (int q = 0; q < 8; ++q) {
        acc = fmaf(v[q].x, w[4 * q + 0], acc);
        acc = fmaf(v[q].y, w[4 * q + 1], acc);
        acc = fmaf(v[q].z, w[4 * q + 2], acc);
        acc = fmaf(v[q].w, w[4 * q + 3], acc);
    }
    return acc;
}
#endif

__global__
#if USE_FDOT2
__launch_bounds__(256, 4)   // cap VGPRs at 128 -> 4 waves/SIMD
#else
__launch_bounds__(256, 2)
#endif
void gather_conv_kernel(
    const float* __restrict__ feat, const float* __restrict__ weight,
    const int4* __restrict__ table, float* __restrict__ out,
    float* __restrict__ stats, int n_out)
{
    const int lane = threadIdx.x & 63;
    const int wv   = threadIdx.x >> 6;

#if USE_FDOT2
    h2 w0[16], w1[16], w2[16], w3[16];
#pragma unroll
    for (int j = 0; j < 16; ++j) {
        w0[j] = __builtin_amdgcn_cvt_pkrtz(weight[(0 * 32 + 2 * j) * 64 + lane],
                                           weight[(0 * 32 + 2 * j + 1) * 64 + lane]);
        w1[j] = __builtin_amdgcn_cvt_pkrtz(weight[(1 * 32 + 2 * j) * 64 + lane],
                                           weight[(1 * 32 + 2 * j + 1) * 64 + lane]);
        w2[j] = __builtin_amdgcn_cvt_pkrtz(weight[(2 * 32 + 2 * j) * 64 + lane],
                                           weight[(2 * 32 + 2 * j + 1) * 64 + lane]);
        w3[j] = __builtin_amdgcn_cvt_pkrtz(weight[(3 * 32 + 2 * j) * 64 + lane],
                                           weight[(3 * 32 + 2 * j + 1) * 64 + lane]);
    }
#else
    float w0[32], w1[32], w2[32], w3[32];
#pragma unroll
    for (int c = 0; c < 32; ++c) {
        w0[c] = weight[(0 * 32 + c) * 64 + lane];
        w1[c] = weight[(1 * 32 + c) * 64 + lane];
        w2[c] = weight[(2 * 32 + c) * 64 + lane];
        w3[c] = weight[(3 * 32 + c) * 64 + lane];
    }
#endif

    const int gw = blockIdx.x * 4 + wv;
    const int nw = gridDim.x * 4;
    float s = 0.f, ss = 0.f;

    int o = gw;
    if (o < n_out) {
        int4 sl = table[o];
        while (o < n_out) {
            const int on = o + nw;
            int4 sln = make_int4(-1, -1, -1, -1);
            if (on < n_out) sln = table[on];          // slot prefetch
            float acc = 0.f;
            if (sl.x >= 0) acc = dot_row(feat + (size_t)sl.x * 32, w0, acc);
            if (sl.y >= 0) acc = dot_row(feat + (size_t)sl.y * 32, w1, acc);
            if (sl.z >= 0) acc = dot_row(feat + (size_t)sl.z * 32, w2, acc);
            if (sl.w >= 0) acc = dot_row(feat + (size_t)sl.w * 32, w3, acc);
            out[(size_t)o * 64 + lane] = acc;          // single coalesced store
            s += acc;
            ss = fmaf(acc, acc, ss);
            o = on;
            sl = sln;
        }
    }

    __shared__ float ls[4][64];
    __shared__ float lq[4][64];
    ls[wv][lane] = s;
    lq[wv][lane] = ss;
    __syncthreads();
    if (wv == 0) {
        float ts = ls[0][lane] + ls[1][lane] + ls[2][lane] + ls[3][lane];
        float tq = lq[0][lane] + lq[1][lane] + lq[2][lane] + lq[3][lane];
        atomicAdd(&stats[lane], ts);
        atomicAdd(&stats[64 + lane], tq);
    }
}

// ---------------------------------------------------------------------------
__global__ void finalize_kernel(float* __restrict__ stats,
                                const float* __restrict__ gamma,
                                const float* __restrict__ beta, float inv_n)
{
    const int j = threadIdx.x;  // 64 threads
    float mean = stats[j] * inv_n;
    float var  = fmaf(-mean, mean, stats[64 + j] * inv_n);
    var = fmaxf(var, 0.f);
    float scale = gamma[j] * rsqrtf(var + BN_EPS);
    stats[128 + j] = scale;
    stats[192 + j] = beta[j] - mean * scale;
}

__global__ __launch_bounds__(256) void apply_kernel(
    float* __restrict__ out, const float* __restrict__ stats, int n4)
{
    __shared__ float sscale[64];
    __shared__ float sshift[64];
    if (threadIdx.x < 64) {
        sscale[threadIdx.x] = stats[128 + threadIdx.x];
        sshift[threadIdx.x] = stats[192 + threadIdx.x];
    }
    __syncthreads();
    const int idx = blockIdx.x * blockDim.x + threadIdx.x;
    const int stride = gridDim.x * blockDim.x;
    float4* o4 = (float4*)out;
    for (int i = idx; i < n4; i += stride) {
        const int cb = (i * 4) & 63;  // stride*4 % 64 == 0 -> fixed per thread
        float4 v = o4[i];
        v.x = fmaf(v.x, sscale[cb + 0], sshift[cb + 0]);
        v.y = fmaf(v.y, sscale[cb + 1], sshift[cb + 1]);
        v.z = fmaf(v.z, sscale[cb + 2], sshift[cb + 2]);
        v.w = fmaf(v.w, sscale[cb + 3], sshift[cb + 3]);
        v.x = v.x > 0.f ? v.x : LEAK * v.x;
        v.y = v.y > 0.f ? v.y : LEAK * v.y;
        v.z = v.z > 0.f ? v.z : LEAK * v.z;
        v.w = v.w > 0.f ? v.w : LEAK * v.w;
        o4[i] = v;
    }
}

// ---------------------------------------------------------------------------
extern "C" void kernel_launch(void* const* d_in, const int* in_sizes, int n_in,
                              void* d_out, int out_size, void* d_ws, size_t ws_size,
                              hipStream_t stream)
{
    // Inputs: 0=features 1=weight 2=bias(cancels in BN) 3=gamma 4=beta
    //         5=out_idx 6=kern_idx 7=n_out(scalar, unused: out_size/64)
    const float* feat     = (const float*)d_in[0];
    const float* weight   = (const float*)d_in[1];
    const float* gamma    = (const float*)d_in[3];
    const float* beta     = (const float*)d_in[4];
    const int*   out_idx  = (const int*)d_in[5];
    const int*   kern_idx = (const int*)d_in[6];
    const int n_active = in_sizes[5];
    const int n_out    = out_size / 64;
    float* out   = (float*)d_out;
    float* stats = (float*)d_ws;                       // 256 floats
    int*   table = (int*)((char*)d_ws + 1024);         // n_out*4 ints

    (void)hipMemsetAsync(stats, 0, 512, stream);       // sums + sumsqs
    (void)hipMemsetAsync(table, 0xFF, (size_t)n_out * 4 * sizeof(int), stream);  // -1

    fill_table_kernel<<<(n_active + 255) / 256, 256, 0, stream>>>(
        out_idx, kern_idx, table, n_active);
    gather_conv_kernel<<<2048, 256, 0, stream>>>(
        feat, weight, (const int4*)table, out, stats, n_out);
    finalize_kernel<<<1, 64, 0, stream>>>(stats, gamma, beta, 1.0f / (float)n_out);
    apply_kernel<<<2048, 256, 0, stream>>>(out, stats, out_size / 4);
}